// Round 7
// baseline (152.724 us; speedup 1.0000x reference)
//
#include <hip/hip_runtime.h>
#include <math.h>

#define D 128
#define H 64
#define W 100
#define R 20
#define NB 256
#define NDOC_UI (NB * R)   // 5120
#define VOCAB 50000

// e^(2x) identity tanh: exact saturation at +-1 via inf/0 in rcp.
__device__ __forceinline__ float fast_tanh(float x) {
    float u = __expf(2.0f * x);
    return 1.0f - 2.0f * __builtin_amdgcn_rcpf(1.0f + u);
}
__device__ __forceinline__ float fast_exp_tanh(float x) {
    return __expf(fast_tanh(x));
}

// fp32 -> bf16 round-to-nearest-even
__device__ __forceinline__ unsigned short f2bf(float f) {
    unsigned int b = __float_as_uint(f);
    b += 0x7fffu + ((b >> 16) & 1u);
    return (unsigned short)(b >> 16);
}

// ---------------- Kernel 0 (fast path): vocab prep ---------------------------
// Score e = exp(tanh(emb_row . w_self + b)) is doc-independent. Precompute per
// vocab row; store PRE-SCALED row e*emb as bf16 (256 B vs 512 B) + evocab[v]=e.
__global__ __launch_bounds__(256) void vocab_prep_kernel(
    const float* __restrict__ emb, const float* __restrict__ w_self,
    const float* __restrict__ b_self,
    ushort* __restrict__ emb_bf, float* __restrict__ evocab)
{
    int tid = threadIdx.x, lane32 = tid & 31, grp = tid >> 5;
    int row = blockIdx.x * 8 + grp;            // 6250 blocks, exact
    float4 v   = ((const float4*)emb)[row * 32 + lane32];
    float4 ws4 = ((const float4*)w_self)[lane32];
    float p = v.x * ws4.x + v.y * ws4.y + v.z * ws4.z + v.w * ws4.w;
    p += __shfl_xor(p, 16, 64);
    p += __shfl_xor(p, 8, 64);
    p += __shfl_xor(p, 4, 64);
    p += __shfl_xor(p, 2, 64);
    p += __shfl_xor(p, 1, 64);
    float e = __expf(tanhf(p + b_self[0]));    // precise tanh: only 50K evals
    if (lane32 == 0) evocab[row] = e;
    ushort4 u;
    u.x = f2bf(v.x * e); u.y = f2bf(v.y * e);
    u.z = f2bf(v.z * e); u.w = f2bf(v.w * e);
    ((ushort4*)emb_bf)[row * 32 + lane32] = u;
}

// ---------------- Kernel A (fast path): doc embed = weighted gather-sum ------
// One 32-lane group per doc, 4 docs per 128-thread block (grid 2624 = 10.25
// blocks/CU for finer tail). Rows pre-scaled bf16 (256 B): 16 lanes x 16 B per
// row -> each dwordx4 covers 2 words; 10 gathers in flight per chunk.
__global__ __launch_bounds__(128) void doc_embed_bf16_kernel(
    const int* __restrict__ user_w, const int* __restrict__ item_w,
    const int* __restrict__ query_w,
    const ushort* __restrict__ emb_bf, const float* __restrict__ evocab,
    float* __restrict__ user_emb, float* __restrict__ item_emb,
    float* __restrict__ q_emb)
{
    int tid    = threadIdx.x;
    int lane32 = tid & 31;
    int grp    = tid >> 5;                 // 0..3
    int doc    = blockIdx.x * 4 + grp;     // 10496 = 2624*4 exactly

    const int* wp; float* outp;
    if (doc < NDOC_UI)        { wp = user_w + doc * W;               outp = user_emb + doc * D; }
    else if (doc < 2*NDOC_UI) { int t = doc - NDOC_UI;   wp = item_w  + t * W; outp = item_emb + t * D; }
    else                      { int t = doc - 2*NDOC_UI; wp = query_w + t * W; outp = q_emb    + t * D; }

    // Word ids: wreg[k] lane l holds words[k*32+l] (clamped dup for tail).
    int wreg[4];
    #pragma unroll
    for (int k = 0; k < 4; ++k) {
        int idx = k * 32 + lane32;
        wreg[k] = wp[idx > W - 1 ? W - 1 : idx];
    }

    // esum: gather evocab (200 KB, cache-resident), mask tail, 5-shuffle reduce.
    float ep = 0.f;
    #pragma unroll
    for (int k = 0; k < 4; ++k) {
        float e = evocab[wreg[k]];
        if (k < 3 || lane32 < 4) ep += e;
    }
    ep += __shfl_xor(ep, 16, 64);
    ep += __shfl_xor(ep, 8, 64);
    ep += __shfl_xor(ep, 4, 64);
    ep += __shfl_xor(ep, 2, 64);
    ep += __shfl_xor(ep, 1, 64);
    float inv = 1.f / ep;

    int permbase = (tid & 32) << 2;        // bpermute byte base of my 32-half
    int sub      = lane32 >> 4;            // which word of the pair (0/1)
    int quad     = lane32 & 15;            // 16B slice within the row

    float acc[8];
    #pragma unroll
    for (int j = 0; j < 8; ++j) acc[j] = 0.f;

    const uint4* ebf4 = (const uint4*)emb_bf;

    // 50 pair-slots: slot s covers words {2s, 2s+1}; chunks of 10 in flight.
    #pragma unroll
    for (int c = 0; c < 5; ++c) {
        int wid[10]; uint4 v[10];
        #pragma unroll
        for (int j = 0; j < 10; ++j) {
            int s = c * 10 + j;
            int lane_src = ((2 * s) & 31) | sub;      // (2s+sub)&31, 2s even
            wid[j] = __builtin_amdgcn_ds_bpermute(permbase | (lane_src << 2),
                                                  wreg[s >> 4]);
        }
        #pragma unroll
        for (int j = 0; j < 10; ++j)
            v[j] = ebf4[(size_t)(unsigned)wid[j] * 16 + quad];
        #pragma unroll
        for (int j = 0; j < 10; ++j) {
            uint4 x = v[j];
            acc[0] += __uint_as_float(x.x << 16);
            acc[1] += __uint_as_float(x.x & 0xffff0000u);
            acc[2] += __uint_as_float(x.y << 16);
            acc[3] += __uint_as_float(x.y & 0xffff0000u);
            acc[4] += __uint_as_float(x.z << 16);
            acc[5] += __uint_as_float(x.z & 0xffff0000u);
            acc[6] += __uint_as_float(x.w << 16);
            acc[7] += __uint_as_float(x.w & 0xffff0000u);
        }
    }

    // Combine the two 16-lane word-subsets, scale, store (lanes 0..15).
    #pragma unroll
    for (int j = 0; j < 8; ++j) acc[j] += __shfl_xor(acc[j], 16, 64);

    if (lane32 < 16) {
        float4 o0 = make_float4(acc[0]*inv, acc[1]*inv, acc[2]*inv, acc[3]*inv);
        float4 o1 = make_float4(acc[4]*inv, acc[5]*inv, acc[6]*inv, acc[7]*inv);
        ((float4*)outp)[quad * 2]     = o0;
        ((float4*)outp)[quad * 2 + 1] = o1;
    }
}

// ---------------- Kernel A' (fallback, R4-proven): fp32 gather doc embed -----
__global__ __launch_bounds__(256, 7) void doc_embed_fp32_kernel(
    const int* __restrict__ user_w, const int* __restrict__ item_w,
    const int* __restrict__ query_w,
    const float* __restrict__ emb, const float* __restrict__ w_self,
    const float* __restrict__ b_self,
    float* __restrict__ user_emb, float* __restrict__ item_emb,
    float* __restrict__ q_emb)
{
    int tid    = threadIdx.x;
    int lane32 = tid & 31;
    int grp    = tid >> 5;
    int doc    = blockIdx.x * 8 + grp;

    const int* wp; float* outp;
    if (doc < NDOC_UI)        { wp = user_w + doc * W;               outp = user_emb + doc * D; }
    else if (doc < 2*NDOC_UI) { int t = doc - NDOC_UI;   wp = item_w  + t * W; outp = item_emb + t * D; }
    else                      { int t = doc - 2*NDOC_UI; wp = query_w + t * W; outp = q_emb    + t * D; }

    int wreg[4];
    #pragma unroll
    for (int k = 0; k < 4; ++k) {
        int idx = k * 32 + lane32;
        wreg[k] = wp[idx > W - 1 ? W - 1 : idx];
    }

    float4 ws4 = ((const float4*)w_self)[lane32];
    float  bs  = b_self[0];
    const float4* emb4 = (const float4*)emb;
    int permbase = (tid & 32) * 4;

    float4 acc  = make_float4(0.f, 0.f, 0.f, 0.f);
    float  esum = 0.f;

    #pragma unroll
    for (int c = 0; c < 10; ++c) {
        int word[10];
        #pragma unroll
        for (int j = 0; j < 10; ++j) {
            int w = c * 10 + j;
            word[j] = __builtin_amdgcn_ds_bpermute(permbase | ((w & 31) * 4),
                                                   wreg[w >> 5]);
        }
        float4 v[10];
        #pragma unroll
        for (int j = 0; j < 10; ++j)
            v[j] = emb4[(size_t)word[j] * 32 + lane32];

        #pragma unroll
        for (int j = 0; j < 10; ++j) {
            float p = v[j].x * ws4.x + v[j].y * ws4.y + v[j].z * ws4.z + v[j].w * ws4.w;
            p += __shfl_xor(p, 16, 64);
            p += __shfl_xor(p, 8, 64);
            p += __shfl_xor(p, 4, 64);
            p += __shfl_xor(p, 2, 64);
            p += __shfl_xor(p, 1, 64);
            float e = fast_exp_tanh(p + bs);
            esum += e;
            acc.x += e * v[j].x;
            acc.y += e * v[j].y;
            acc.z += e * v[j].z;
            acc.w += e * v[j].w;
        }
    }

    float inv = 1.0f / esum;
    acc.x *= inv; acc.y *= inv; acc.z *= inv; acc.w *= inv;
    ((float4*)outp)[lane32] = acc;
}

// ---------------- Kernel B: pv[b,d] = sum_h tanh(q@Wq+bq)[b,d*64+h]*w_red[h] -
// VALU-bound redesign: per-thread tile 8m x 4n (16 mthr x 16 nthr = 256 thr),
// q rows read DIRECT from global (L2-resident, 16-fold wave broadcast) with
// double-buffered k4 prefetch; only Wq staged in LDS (1 b128/k/thread ->
// ~48 DS-cyc vs 256 VALU-cyc per k4 -> VALU-bound). Grid 256 = 1 block/CU,
// 4 waves = 1/SIMD fully busy.
__global__ __launch_bounds__(256) void pv_kernel(
    const float* __restrict__ q_emb, const float* __restrict__ Wq,
    const float* __restrict__ bq, const float* __restrict__ w_red,
    float* __restrict__ pv)
{
    __shared__ __align__(16) float Wb[128 * 68];    // 34.8 KB

    int dd  = blockIdx.x;          // 0..127
    int m0g = blockIdx.y * 128;    // row offset (0 or 128)
    int tid = threadIdx.x;

    // Stage Wq tile: row k -> 64 consecutive floats at Wq[k*8192 + dd*64]
    {
        int rrow = tid >> 4;       // 0..15
        int f4   = tid & 15;       // 0..15
        #pragma unroll
        for (int pass = 0; pass < 8; ++pass) {
            int k = pass * 16 + rrow;
            float4 vw = ((const float4*)Wq)[k * 2048 + dd * 16 + f4];
            *(float4*)&Wb[k * 68 + f4 * 4] = vw;
        }
    }
    __syncthreads();

    int nthr = tid & 15;           // n0 = nthr*4
    int mthr = tid >> 4;           // m0 = mthr*8
    int n0 = nthr * 4;
    const float4* q4 = (const float4*)q_emb;
    int mbase = (m0g + mthr * 8) * 32;      // float4 index of row m0, k4=0

    float acc[8][4];
    #pragma unroll
    for (int i = 0; i < 8; ++i)
        #pragma unroll
        for (int j = 0; j < 4; ++j) acc[i][j] = 0.f;

    float4 qa[8], qb[8];
    #pragma unroll
    for (int i = 0; i < 8; ++i) qa[i] = q4[mbase + i * 32];   // k4 = 0

    for (int k4 = 0; k4 < 32; ++k4) {
        // Prefetch next k4's q slices while computing this one.
        if (k4 < 31) {
            #pragma unroll
            for (int i = 0; i < 8; ++i) qb[i] = q4[mbase + i * 32 + k4 + 1];
        }
        #pragma unroll
        for (int kk = 0; kk < 4; ++kk) {
            float4 wv = *(const float4*)&Wb[(k4 * 4 + kk) * 68 + n0];
            #pragma unroll
            for (int i = 0; i < 8; ++i) {
                float a = (kk == 0) ? qa[i].x : (kk == 1) ? qa[i].y
                        : (kk == 2) ? qa[i].z : qa[i].w;
                acc[i][0] += a * wv.x;
                acc[i][1] += a * wv.y;
                acc[i][2] += a * wv.z;
                acc[i][3] += a * wv.w;
            }
        }
        #pragma unroll
        for (int i = 0; i < 8; ++i) qa[i] = qb[i];
    }

    // Epilogue: tanh(+bq)*w_red, reduce across the 16 n-threads (lane bits 0..3)
    float4 bqv = ((const float4*)bq)[dd * 16 + nthr];
    float4 wrv = ((const float4*)w_red)[nthr];

    #pragma unroll
    for (int i = 0; i < 8; ++i) {
        float s = fast_tanh(acc[i][0] + bqv.x) * wrv.x
                + fast_tanh(acc[i][1] + bqv.y) * wrv.y
                + fast_tanh(acc[i][2] + bqv.z) * wrv.z
                + fast_tanh(acc[i][3] + bqv.w) * wrv.w;
        s += __shfl_xor(s, 1, 64);
        s += __shfl_xor(s, 2, 64);
        s += __shfl_xor(s, 4, 64);
        s += __shfl_xor(s, 8, 64);
        if (nthr == 0) pv[(m0g + mthr * 8 + i) * 128 + dd] = s;
    }
}

// ---------------- Kernel C: review attention + output ------------------------
__global__ __launch_bounds__(256) void attn_kernel(
    const float* __restrict__ user_emb, const float* __restrict__ item_emb,
    const float* __restrict__ q_emb, const float* __restrict__ pv,
    const float* __restrict__ pf, float* __restrict__ out)
{
    __shared__ float rev[R * 129];
    __shared__ float pvl[D];
    __shared__ float sc[R];

    int b   = blockIdx.x;
    int set = blockIdx.y;
    const float* revg = (set == 0 ? user_emb : item_emb) + b * R * D;
    int tid = threadIdx.x;

    for (int idx = tid; idx < R * D; idx += 256)
        rev[(idx >> 7) * 129 + (idx & 127)] = revg[idx];
    if (tid < D) pvl[tid] = pv[b * D + tid];
    __syncthreads();

    if (tid < R) {
        float s = 0.f;
        const float* row = &rev[tid * 129];
        #pragma unroll 16
        for (int k = 0; k < D; ++k) s += row[k] * pvl[k];
        sc[tid] = s;
    }
    __syncthreads();

    float m = -1e30f;
    for (int r = 0; r < R; ++r) m = fmaxf(m, sc[r]);
    float sum = 0.f;
    for (int r = 0; r < R; ++r) sum += __expf(sc[r] - m);
    float inv = 1.f / sum;

    if (tid < D) {
        float acc = 0.f;
        for (int r = 0; r < R; ++r)
            acc += __expf(sc[r] - m) * inv * rev[r * 129 + tid];
        if (set == 0) {
            acc += pf[0] * q_emb[b * D + tid];
            out[b * D + tid] = acc;
        } else {
            out[NB * D + b * D + tid] = acc;
        }
    }
}

extern "C" void kernel_launch(void* const* d_in, const int* in_sizes, int n_in,
                              void* d_out, int out_size, void* d_ws, size_t ws_size,
                              hipStream_t stream) {
    const int*   user_w  = (const int*)d_in[0];
    const int*   item_w  = (const int*)d_in[1];
    const int*   query_w = (const int*)d_in[2];
    const float* emb     = (const float*)d_in[3];
    const float* w_self  = (const float*)d_in[4];
    const float* b_self  = (const float*)d_in[5];
    const float* Wq      = (const float*)d_in[6];
    const float* bq      = (const float*)d_in[7];
    const float* w_red   = (const float*)d_in[8];
    const float* pf      = (const float*)d_in[9];

    float* ws       = (float*)d_ws;
    float* user_emb = ws;                          // 5120*128
    float* item_emb = user_emb + NDOC_UI * D;      // 5120*128
    float* q_emb    = item_emb + NDOC_UI * D;      // 256*128
    float* pv       = q_emb    + NB * D;           // 256*128
    float* evocab   = pv       + NB * D;           // 50000
    ushort* emb_bf  = (ushort*)(evocab + VOCAB);   // 50000*128 bf16 = 12.8 MB
    float* out      = (float*)d_out;

    // Fast path needs the bf16 vocab table in ws; guard against small ws.
    const size_t need_fast =
        (size_t)(2 * NDOC_UI * D + 2 * NB * D + VOCAB) * sizeof(float)
        + (size_t)VOCAB * D * sizeof(ushort);      // 18,505,024 B

    if (ws_size >= need_fast) {
        vocab_prep_kernel<<<VOCAB / 8, 256, 0, stream>>>(
            emb, w_self, b_self, emb_bf, evocab);
        doc_embed_bf16_kernel<<<(2 * NDOC_UI + NB) / 4, 128, 0, stream>>>(
            user_w, item_w, query_w, emb_bf, evocab, user_emb, item_emb, q_emb);
    } else {
        doc_embed_fp32_kernel<<<(2 * NDOC_UI + NB) / 8, 256, 0, stream>>>(
            user_w, item_w, query_w, emb, w_self, b_self, user_emb, item_emb, q_emb);
    }
    pv_kernel<<<dim3(128, 2), 256, 0, stream>>>(q_emb, Wq, bq, w_red, pv);
    attn_kernel<<<dim3(NB, 2), 256, 0, stream>>>(user_emb, item_emb, q_emb, pv, pf, out);
}

// Round 8
// 149.032 us; speedup vs baseline: 1.0248x; 1.0248x over previous
//
#include <hip/hip_runtime.h>
#include <math.h>

#define D 128
#define H 64
#define W 100
#define R 20
#define NB 256
#define NDOC_UI (NB * R)   // 5120
#define NDOC    (2 * NDOC_UI + NB)   // 10496
#define VOCAB 50000

// e^(2x) identity tanh: exact saturation at +-1 via inf/0 in rcp.
__device__ __forceinline__ float fast_tanh(float x) {
    float u = __expf(2.0f * x);
    return 1.0f - 2.0f * __builtin_amdgcn_rcpf(1.0f + u);
}
__device__ __forceinline__ float fast_exp_tanh(float x) {
    return __expf(fast_tanh(x));
}

// fp32 -> bf16 round-to-nearest-even
__device__ __forceinline__ unsigned short f2bf(float f) {
    unsigned int b = __float_as_uint(f);
    b += 0x7fffu + ((b >> 16) & 1u);
    return (unsigned short)(b >> 16);
}

// ---------------- Kernel 0 (fast path): vocab prep ---------------------------
// e = exp(tanh(emb_row . w_self + b)) is doc-independent. Precompute per vocab
// row; store PRE-SCALED e*emb as bf16 in TWO D-half tables (6.4 MB each) so
// doc_embed can pin each half to an XCD group (per-XCD L2 footprint 6.4 MB).
__global__ __launch_bounds__(256) void vocab_prep_kernel(
    const float* __restrict__ emb, const float* __restrict__ w_self,
    const float* __restrict__ b_self,
    ushort* __restrict__ emb_bf, float* __restrict__ evocab)
{
    int tid = threadIdx.x, lane32 = tid & 31, grp = tid >> 5;
    int row = blockIdx.x * 8 + grp;            // 6250 blocks, exact
    float4 v   = ((const float4*)emb)[row * 32 + lane32];
    float4 ws4 = ((const float4*)w_self)[lane32];
    float p = v.x * ws4.x + v.y * ws4.y + v.z * ws4.z + v.w * ws4.w;
    p += __shfl_xor(p, 16, 64);
    p += __shfl_xor(p, 8, 64);
    p += __shfl_xor(p, 4, 64);
    p += __shfl_xor(p, 2, 64);
    p += __shfl_xor(p, 1, 64);
    float e = __expf(tanhf(p + b_self[0]));    // precise tanh: only 50K evals
    if (lane32 == 0) evocab[row] = e;
    ushort4 u;
    u.x = f2bf(v.x * e); u.y = f2bf(v.y * e);
    u.z = f2bf(v.z * e); u.w = f2bf(v.w * e);
    int half = lane32 >> 4;                    // d-half this lane belongs to
    ushort4* dst = (ushort4*)(emb_bf + (size_t)half * VOCAB * 64);
    dst[row * 16 + (lane32 & 15)] = u;
}

// ---------------- Kernel A (fast path): doc embed = weighted gather-sum ------
// One 32-lane group handles one (doc, d-half): 8 lanes x 16 B cover the 128 B
// half-row, 4 words per load-slot, 25 slots exactly (100 = 25*4, no tail).
// XCD pinning: blockIdx%8 is (heuristically) the XCD; XCDs 0-3 -> half 0,
// XCDs 4-7 -> half 1, so each XCD's L2 sees only a 6.4 MB table. Correctness
// does not depend on the mapping (each doc-half computed exactly once).
__global__ __launch_bounds__(128) void doc_embed_bf16_kernel(
    const int* __restrict__ user_w, const int* __restrict__ item_w,
    const int* __restrict__ query_w,
    const ushort* __restrict__ emb_bf, const float* __restrict__ evocab,
    float* __restrict__ user_emb, float* __restrict__ item_emb,
    float* __restrict__ q_emb)
{
    int tid    = threadIdx.x;
    int lane32 = tid & 31;
    int grp    = tid >> 5;                 // 0..3
    unsigned B   = blockIdx.x;             // 5248 blocks = 656 * 8
    unsigned xcd = B & 7;
    unsigned half= xcd >> 2;               // 0 or 1
    unsigned sub = (B >> 3) * 4 + (xcd & 3);   // [0, 2624)
    int doc = (int)sub * 4 + grp;          // [0, 10496)

    const int* wp; float* outp;
    if (doc < NDOC_UI)        { wp = user_w + doc * W;               outp = user_emb + doc * D; }
    else if (doc < 2*NDOC_UI) { int t = doc - NDOC_UI;   wp = item_w  + t * W; outp = item_emb + t * D; }
    else                      { int t = doc - 2*NDOC_UI; wp = query_w + t * W; outp = q_emb    + t * D; }

    // Word ids: wreg[k] lane l holds words[k*32+l] (clamped dup for tail).
    int wreg[4];
    #pragma unroll
    for (int k = 0; k < 4; ++k) {
        int idx = k * 32 + lane32;
        wreg[k] = wp[idx > W - 1 ? W - 1 : idx];
    }

    // esum: gather evocab (200 KB, cache-resident), mask tail, 5-shuffle reduce.
    float ep = 0.f;
    #pragma unroll
    for (int k = 0; k < 4; ++k) {
        float e = evocab[wreg[k]];
        if (k < 3 || lane32 < 4) ep += e;
    }
    ep += __shfl_xor(ep, 16, 64);
    ep += __shfl_xor(ep, 8, 64);
    ep += __shfl_xor(ep, 4, 64);
    ep += __shfl_xor(ep, 2, 64);
    ep += __shfl_xor(ep, 1, 64);
    float inv = 1.f / ep;

    int permbase = (tid & 32) << 2;        // bpermute byte base of my 32-half
    int wsub     = lane32 >> 3;            // which word of the 4-word slot
    int oct      = lane32 & 7;             // 16 B slice within the 128 B half-row

    float acc[8];
    #pragma unroll
    for (int j = 0; j < 8; ++j) acc[j] = 0.f;

    const uint4* eb4 = (const uint4*)(emb_bf + (size_t)half * VOCAB * 64);

    // 25 slots; slot s covers words 4s..4s+3 (section s>>3 is slot-uniform).
    #pragma unroll
    for (int c = 0; c < 2; ++c) {
        const int n = (c == 0) ? 13 : 12;
        const int s0 = (c == 0) ? 0 : 13;
        int wid[13]; uint4 v[13];
        for (int j = 0; j < n; ++j) {
            int s = s0 + j;
            wid[j] = __builtin_amdgcn_ds_bpermute(
                permbase | ((((4 * s) & 31) + wsub) << 2), wreg[s >> 3]);
        }
        for (int j = 0; j < n; ++j)
            v[j] = eb4[(size_t)(unsigned)wid[j] * 8 + oct];
        for (int j = 0; j < n; ++j) {
            uint4 x = v[j];
            acc[0] += __uint_as_float(x.x << 16);
            acc[1] += __uint_as_float(x.x & 0xffff0000u);
            acc[2] += __uint_as_float(x.y << 16);
            acc[3] += __uint_as_float(x.y & 0xffff0000u);
            acc[4] += __uint_as_float(x.z << 16);
            acc[5] += __uint_as_float(x.z & 0xffff0000u);
            acc[6] += __uint_as_float(x.w << 16);
            acc[7] += __uint_as_float(x.w & 0xffff0000u);
        }
    }

    // Reduce over the 4 word-subgroups (xor 8, 16 within the 32-lane group).
    #pragma unroll
    for (int j = 0; j < 8; ++j) {
        acc[j] += __shfl_xor(acc[j], 8, 64);
        acc[j] += __shfl_xor(acc[j], 16, 64);
    }

    if (wsub == 0) {   // lanes 0..7 of the group hold dims oct*8..oct*8+7
        float* o = outp + half * 64 + oct * 8;
        *(float4*)o       = make_float4(acc[0]*inv, acc[1]*inv, acc[2]*inv, acc[3]*inv);
        *(float4*)(o + 4) = make_float4(acc[4]*inv, acc[5]*inv, acc[6]*inv, acc[7]*inv);
    }
}

// ---------------- Kernel A' (fallback, R4-proven): fp32 gather doc embed -----
__global__ __launch_bounds__(256, 7) void doc_embed_fp32_kernel(
    const int* __restrict__ user_w, const int* __restrict__ item_w,
    const int* __restrict__ query_w,
    const float* __restrict__ emb, const float* __restrict__ w_self,
    const float* __restrict__ b_self,
    float* __restrict__ user_emb, float* __restrict__ item_emb,
    float* __restrict__ q_emb)
{
    int tid    = threadIdx.x;
    int lane32 = tid & 31;
    int grp    = tid >> 5;
    int doc    = blockIdx.x * 8 + grp;

    const int* wp; float* outp;
    if (doc < NDOC_UI)        { wp = user_w + doc * W;               outp = user_emb + doc * D; }
    else if (doc < 2*NDOC_UI) { int t = doc - NDOC_UI;   wp = item_w  + t * W; outp = item_emb + t * D; }
    else                      { int t = doc - 2*NDOC_UI; wp = query_w + t * W; outp = q_emb    + t * D; }

    int wreg[4];
    #pragma unroll
    for (int k = 0; k < 4; ++k) {
        int idx = k * 32 + lane32;
        wreg[k] = wp[idx > W - 1 ? W - 1 : idx];
    }

    float4 ws4 = ((const float4*)w_self)[lane32];
    float  bs  = b_self[0];
    const float4* emb4 = (const float4*)emb;
    int permbase = (tid & 32) * 4;

    float4 acc  = make_float4(0.f, 0.f, 0.f, 0.f);
    float  esum = 0.f;

    #pragma unroll
    for (int c = 0; c < 10; ++c) {
        int word[10];
        #pragma unroll
        for (int j = 0; j < 10; ++j) {
            int w = c * 10 + j;
            word[j] = __builtin_amdgcn_ds_bpermute(permbase | ((w & 31) * 4),
                                                   wreg[w >> 5]);
        }
        float4 v[10];
        #pragma unroll
        for (int j = 0; j < 10; ++j)
            v[j] = emb4[(size_t)word[j] * 32 + lane32];

        #pragma unroll
        for (int j = 0; j < 10; ++j) {
            float p = v[j].x * ws4.x + v[j].y * ws4.y + v[j].z * ws4.z + v[j].w * ws4.w;
            p += __shfl_xor(p, 16, 64);
            p += __shfl_xor(p, 8, 64);
            p += __shfl_xor(p, 4, 64);
            p += __shfl_xor(p, 2, 64);
            p += __shfl_xor(p, 1, 64);
            float e = fast_exp_tanh(p + bs);
            esum += e;
            acc.x += e * v[j].x;
            acc.y += e * v[j].y;
            acc.z += e * v[j].z;
            acc.w += e * v[j].w;
        }
    }

    float inv = 1.0f / esum;
    acc.x *= inv; acc.y *= inv; acc.z *= inv; acc.w *= inv;
    ((float4*)outp)[lane32] = acc;
}

// ---------------- Kernel B: pv[b,d] = sum_h tanh(q@Wq+bq)[b,d*64+h]*w_red[h] -
// Per-thread tile 8m x 4n; q rows direct from global (L2-resident, broadcast),
// double-buffered k4 prefetch; only Wq staged in LDS.
__global__ __launch_bounds__(256) void pv_kernel(
    const float* __restrict__ q_emb, const float* __restrict__ Wq,
    const float* __restrict__ bq, const float* __restrict__ w_red,
    float* __restrict__ pv)
{
    __shared__ __align__(16) float Wb[128 * 68];    // 34.8 KB

    int dd  = blockIdx.x;          // 0..127
    int m0g = blockIdx.y * 128;    // row offset (0 or 128)
    int tid = threadIdx.x;

    {
        int rrow = tid >> 4;
        int f4   = tid & 15;
        #pragma unroll
        for (int pass = 0; pass < 8; ++pass) {
            int k = pass * 16 + rrow;
            float4 vw = ((const float4*)Wq)[k * 2048 + dd * 16 + f4];
            *(float4*)&Wb[k * 68 + f4 * 4] = vw;
        }
    }
    __syncthreads();

    int nthr = tid & 15;
    int mthr = tid >> 4;
    int n0 = nthr * 4;
    const float4* q4 = (const float4*)q_emb;
    int mbase = (m0g + mthr * 8) * 32;

    float acc[8][4];
    #pragma unroll
    for (int i = 0; i < 8; ++i)
        #pragma unroll
        for (int j = 0; j < 4; ++j) acc[i][j] = 0.f;

    float4 qa[8], qb[8];
    #pragma unroll
    for (int i = 0; i < 8; ++i) qa[i] = q4[mbase + i * 32];

    for (int k4 = 0; k4 < 32; ++k4) {
        if (k4 < 31) {
            #pragma unroll
            for (int i = 0; i < 8; ++i) qb[i] = q4[mbase + i * 32 + k4 + 1];
        }
        #pragma unroll
        for (int kk = 0; kk < 4; ++kk) {
            float4 wv = *(const float4*)&Wb[(k4 * 4 + kk) * 68 + n0];
            #pragma unroll
            for (int i = 0; i < 8; ++i) {
                float a = (kk == 0) ? qa[i].x : (kk == 1) ? qa[i].y
                        : (kk == 2) ? qa[i].z : qa[i].w;
                acc[i][0] += a * wv.x;
                acc[i][1] += a * wv.y;
                acc[i][2] += a * wv.z;
                acc[i][3] += a * wv.w;
            }
        }
        #pragma unroll
        for (int i = 0; i < 8; ++i) qa[i] = qb[i];
    }

    float4 bqv = ((const float4*)bq)[dd * 16 + nthr];
    float4 wrv = ((const float4*)w_red)[nthr];

    #pragma unroll
    for (int i = 0; i < 8; ++i) {
        float s = fast_tanh(acc[i][0] + bqv.x) * wrv.x
                + fast_tanh(acc[i][1] + bqv.y) * wrv.y
                + fast_tanh(acc[i][2] + bqv.z) * wrv.z
                + fast_tanh(acc[i][3] + bqv.w) * wrv.w;
        s += __shfl_xor(s, 1, 64);
        s += __shfl_xor(s, 2, 64);
        s += __shfl_xor(s, 4, 64);
        s += __shfl_xor(s, 8, 64);
        if (nthr == 0) pv[(m0g + mthr * 8 + i) * 128 + dd] = s;
    }
}

// ---------------- Kernel C: review attention + output ------------------------
__global__ __launch_bounds__(256) void attn_kernel(
    const float* __restrict__ user_emb, const float* __restrict__ item_emb,
    const float* __restrict__ q_emb, const float* __restrict__ pv,
    const float* __restrict__ pf, float* __restrict__ out)
{
    __shared__ float rev[R * 129];
    __shared__ float pvl[D];
    __shared__ float sc[R];

    int b   = blockIdx.x;
    int set = blockIdx.y;
    const float* revg = (set == 0 ? user_emb : item_emb) + b * R * D;
    int tid = threadIdx.x;

    for (int idx = tid; idx < R * D; idx += 256)
        rev[(idx >> 7) * 129 + (idx & 127)] = revg[idx];
    if (tid < D) pvl[tid] = pv[b * D + tid];
    __syncthreads();

    if (tid < R) {
        float s = 0.f;
        const float* row = &rev[tid * 129];
        #pragma unroll 16
        for (int k = 0; k < D; ++k) s += row[k] * pvl[k];
        sc[tid] = s;
    }
    __syncthreads();

    float m = -1e30f;
    for (int r = 0; r < R; ++r) m = fmaxf(m, sc[r]);
    float sum = 0.f;
    for (int r = 0; r < R; ++r) sum += __expf(sc[r] - m);
    float inv = 1.f / sum;

    if (tid < D) {
        float acc = 0.f;
        for (int r = 0; r < R; ++r)
            acc += __expf(sc[r] - m) * inv * rev[r * 129 + tid];
        if (set == 0) {
            acc += pf[0] * q_emb[b * D + tid];
            out[b * D + tid] = acc;
        } else {
            out[NB * D + b * D + tid] = acc;
        }
    }
}

extern "C" void kernel_launch(void* const* d_in, const int* in_sizes, int n_in,
                              void* d_out, int out_size, void* d_ws, size_t ws_size,
                              hipStream_t stream) {
    const int*   user_w  = (const int*)d_in[0];
    const int*   item_w  = (const int*)d_in[1];
    const int*   query_w = (const int*)d_in[2];
    const float* emb     = (const float*)d_in[3];
    const float* w_self  = (const float*)d_in[4];
    const float* b_self  = (const float*)d_in[5];
    const float* Wq      = (const float*)d_in[6];
    const float* bq      = (const float*)d_in[7];
    const float* w_red   = (const float*)d_in[8];
    const float* pf      = (const float*)d_in[9];

    float* ws       = (float*)d_ws;
    float* user_emb = ws;                          // 5120*128
    float* item_emb = user_emb + NDOC_UI * D;      // 5120*128
    float* q_emb    = item_emb + NDOC_UI * D;      // 256*128
    float* pv       = q_emb    + NB * D;           // 256*128
    float* evocab   = pv       + NB * D;           // 50000
    ushort* emb_bf  = (ushort*)(evocab + VOCAB);   // 2 half-tables, 12.8 MB
    float* out      = (float*)d_out;

    // Fast path needs the bf16 vocab table in ws; guard against small ws.
    const size_t need_fast =
        (size_t)(2 * NDOC_UI * D + 2 * NB * D + VOCAB) * sizeof(float)
        + (size_t)VOCAB * D * sizeof(ushort);      // 18,505,024 B

    if (ws_size >= need_fast) {
        vocab_prep_kernel<<<VOCAB / 8, 256, 0, stream>>>(
            emb, w_self, b_self, emb_bf, evocab);
        doc_embed_bf16_kernel<<<NDOC * 2 / 4, 128, 0, stream>>>(
            user_w, item_w, query_w, emb_bf, evocab, user_emb, item_emb, q_emb);
    } else {
        doc_embed_fp32_kernel<<<NDOC / 8, 256, 0, stream>>>(
            user_w, item_w, query_w, emb, w_self, b_self, user_emb, item_emb, q_emb);
    }
    pv_kernel<<<dim3(128, 2), 256, 0, stream>>>(q_emb, Wq, bq, w_red, pv);
    attn_kernel<<<dim3(NB, 2), 256, 0, stream>>>(user_emb, item_emb, q_emb, pv, pf, out);
}

// Round 9
// 146.962 us; speedup vs baseline: 1.0392x; 1.0141x over previous
//
#include <hip/hip_runtime.h>
#include <math.h>

#define D 128
#define H 64
#define W 100
#define R 20
#define NB 256
#define NDOC_UI (NB * R)   // 5120
#define NDOC    (2 * NDOC_UI + NB)   // 10496
#define VOCAB 50000

// e^(2x) identity tanh: exact saturation at +-1 via inf/0 in rcp.
__device__ __forceinline__ float fast_tanh(float x) {
    float u = __expf(2.0f * x);
    return 1.0f - 2.0f * __builtin_amdgcn_rcpf(1.0f + u);
}
__device__ __forceinline__ float fast_exp_tanh(float x) {
    return __expf(fast_tanh(x));
}

// fp32 -> bf16 round-to-nearest-even
__device__ __forceinline__ unsigned short f2bf(float f) {
    unsigned int b = __float_as_uint(f);
    b += 0x7fffu + ((b >> 16) & 1u);
    return (unsigned short)(b >> 16);
}

// ---------------- Kernel 0 (fast path): vocab prep ---------------------------
// e = exp(tanh(emb_row . w_self + b)) is doc-independent. Precompute per vocab
// row; store PRE-SCALED e*emb as bf16 in FOUR D-quarter tables (3.2 MB each,
// < 4 MiB per-XCD L2) so doc_embed can pin each quarter to an XCD pair.
__global__ __launch_bounds__(256) void vocab_prep_kernel(
    const float* __restrict__ emb, const float* __restrict__ w_self,
    const float* __restrict__ b_self,
    ushort* __restrict__ emb_bf, float* __restrict__ evocab)
{
    int tid = threadIdx.x, lane32 = tid & 31, grp = tid >> 5;
    int row = blockIdx.x * 8 + grp;            // 6250 blocks, exact
    float4 v   = ((const float4*)emb)[row * 32 + lane32];
    float4 ws4 = ((const float4*)w_self)[lane32];
    float p = v.x * ws4.x + v.y * ws4.y + v.z * ws4.z + v.w * ws4.w;
    p += __shfl_xor(p, 16, 64);
    p += __shfl_xor(p, 8, 64);
    p += __shfl_xor(p, 4, 64);
    p += __shfl_xor(p, 2, 64);
    p += __shfl_xor(p, 1, 64);
    float e = __expf(tanhf(p + b_self[0]));    // precise tanh: only 50K evals
    if (lane32 == 0) evocab[row] = e;
    ushort4 u;
    u.x = f2bf(v.x * e); u.y = f2bf(v.y * e);
    u.z = f2bf(v.z * e); u.w = f2bf(v.w * e);
    int q = lane32 >> 3;                       // d-quarter this lane belongs to
    ushort4* dst = (ushort4*)(emb_bf + (size_t)q * VOCAB * 32);
    dst[row * 8 + (lane32 & 7)] = u;
}

// ---------------- Kernel A (fast path): doc embed = weighted gather-sum ------
// One 32-lane group handles one (doc, d-quarter): 4 lanes x 16 B cover the
// 64 B quarter-row, 8 words per load-slot, 13 slots (last tail-masked).
// XCD pinning: blockIdx%8 ~ XCD; quarter = (B&7)>>1 -> per-XCD table
// footprint 3.2 MB < 4 MiB L2 -> table becomes L2-resident. Correctness does
// not depend on the mapping (each (doc,quarter) computed exactly once).
__global__ __launch_bounds__(128) void doc_embed_bf16_kernel(
    const int* __restrict__ user_w, const int* __restrict__ item_w,
    const int* __restrict__ query_w,
    const ushort* __restrict__ emb_bf, const float* __restrict__ evocab,
    float* __restrict__ user_emb, float* __restrict__ item_emb,
    float* __restrict__ q_emb)
{
    int tid    = threadIdx.x;
    int lane32 = tid & 31;
    int grp    = tid >> 5;                 // 0..3 (doc within block)
    unsigned B    = blockIdx.x;            // 10496 blocks = 1312 * 8
    unsigned quar = (B & 7) >> 1;          // 0..3 (XCD pair -> quarter)
    unsigned sub  = (B >> 3) * 2 + (B & 1);    // [0, 2624)
    int doc = (int)sub * 4 + grp;          // [0, 10496)

    const int* wp; float* outp;
    if (doc < NDOC_UI)        { wp = user_w + doc * W;               outp = user_emb + doc * D; }
    else if (doc < 2*NDOC_UI) { int t = doc - NDOC_UI;   wp = item_w  + t * W; outp = item_emb + t * D; }
    else                      { int t = doc - 2*NDOC_UI; wp = query_w + t * W; outp = q_emb    + t * D; }

    // Word ids: wreg[k] lane l holds words[k*32+l] (clamped dup for tail).
    int wreg[4];
    #pragma unroll
    for (int k = 0; k < 4; ++k) {
        int idx = k * 32 + lane32;
        wreg[k] = wp[idx > W - 1 ? W - 1 : idx];
    }

    // esum: gather evocab (200 KB, cache-resident), mask tail, 5-shuffle reduce.
    float ep = 0.f;
    #pragma unroll
    for (int k = 0; k < 4; ++k) {
        float e = evocab[wreg[k]];
        if (k < 3 || lane32 < 4) ep += e;
    }
    ep += __shfl_xor(ep, 16, 64);
    ep += __shfl_xor(ep, 8, 64);
    ep += __shfl_xor(ep, 4, 64);
    ep += __shfl_xor(ep, 2, 64);
    ep += __shfl_xor(ep, 1, 64);
    float inv = 1.f / ep;

    int permbase = (tid & 32) << 2;        // bpermute byte base of my 32-half
    int wsub     = lane32 >> 2;            // word within the 8-word slot (0..7)
    int sext     = lane32 & 3;             // 16 B slice of the 64 B quarter-row

    float acc[8];
    #pragma unroll
    for (int j = 0; j < 8; ++j) acc[j] = 0.f;

    const uint4* eq4 = (const uint4*)(emb_bf + (size_t)quar * VOCAB * 32);

    // 13 slots; slot s covers words 8s..8s+7 (section s>>2 is slot-uniform;
    // slot 12 covers 96..99 + clamped dups, masked via wsub<4).
    #pragma unroll
    for (int c = 0; c < 2; ++c) {
        const int n  = (c == 0) ? 7 : 6;
        const int s0 = (c == 0) ? 0 : 7;
        int wid[7]; uint4 v[7];
        for (int j = 0; j < n; ++j) {
            int s = s0 + j;
            wid[j] = __builtin_amdgcn_ds_bpermute(
                permbase | ((((8 * s) & 31) + wsub) << 2), wreg[s >> 2]);
        }
        for (int j = 0; j < n; ++j)
            v[j] = eq4[(size_t)(unsigned)wid[j] * 4 + sext];
        for (int j = 0; j < n; ++j) {
            if (s0 + j == 12 && wsub >= 4) break;   // tail mask (lane-static)
            uint4 x = v[j];
            acc[0] += __uint_as_float(x.x << 16);
            acc[1] += __uint_as_float(x.x & 0xffff0000u);
            acc[2] += __uint_as_float(x.y << 16);
            acc[3] += __uint_as_float(x.y & 0xffff0000u);
            acc[4] += __uint_as_float(x.z << 16);
            acc[5] += __uint_as_float(x.z & 0xffff0000u);
            acc[6] += __uint_as_float(x.w << 16);
            acc[7] += __uint_as_float(x.w & 0xffff0000u);
        }
    }

    // Reduce over the 8 word-subgroups (xor 4, 8, 16 within the 32-lane group).
    #pragma unroll
    for (int j = 0; j < 8; ++j) {
        acc[j] += __shfl_xor(acc[j], 4, 64);
        acc[j] += __shfl_xor(acc[j], 8, 64);
        acc[j] += __shfl_xor(acc[j], 16, 64);
    }

    if (wsub == 0) {   // lanes 0..3 hold dims quar*32 + sext*8 .. +7
        float* o = outp + quar * 32 + sext * 8;
        *(float4*)o       = make_float4(acc[0]*inv, acc[1]*inv, acc[2]*inv, acc[3]*inv);
        *(float4*)(o + 4) = make_float4(acc[4]*inv, acc[5]*inv, acc[6]*inv, acc[7]*inv);
    }
}

// ---------------- Kernel A' (fallback, R4-proven): fp32 gather doc embed -----
__global__ __launch_bounds__(256, 7) void doc_embed_fp32_kernel(
    const int* __restrict__ user_w, const int* __restrict__ item_w,
    const int* __restrict__ query_w,
    const float* __restrict__ emb, const float* __restrict__ w_self,
    const float* __restrict__ b_self,
    float* __restrict__ user_emb, float* __restrict__ item_emb,
    float* __restrict__ q_emb)
{
    int tid    = threadIdx.x;
    int lane32 = tid & 31;
    int grp    = tid >> 5;
    int doc    = blockIdx.x * 8 + grp;

    const int* wp; float* outp;
    if (doc < NDOC_UI)        { wp = user_w + doc * W;               outp = user_emb + doc * D; }
    else if (doc < 2*NDOC_UI) { int t = doc - NDOC_UI;   wp = item_w  + t * W; outp = item_emb + t * D; }
    else                      { int t = doc - 2*NDOC_UI; wp = query_w + t * W; outp = q_emb    + t * D; }

    int wreg[4];
    #pragma unroll
    for (int k = 0; k < 4; ++k) {
        int idx = k * 32 + lane32;
        wreg[k] = wp[idx > W - 1 ? W - 1 : idx];
    }

    float4 ws4 = ((const float4*)w_self)[lane32];
    float  bs  = b_self[0];
    const float4* emb4 = (const float4*)emb;
    int permbase = (tid & 32) * 4;

    float4 acc  = make_float4(0.f, 0.f, 0.f, 0.f);
    float  esum = 0.f;

    #pragma unroll
    for (int c = 0; c < 10; ++c) {
        int word[10];
        #pragma unroll
        for (int j = 0; j < 10; ++j) {
            int w = c * 10 + j;
            word[j] = __builtin_amdgcn_ds_bpermute(permbase | ((w & 31) * 4),
                                                   wreg[w >> 5]);
        }
        float4 v[10];
        #pragma unroll
        for (int j = 0; j < 10; ++j)
            v[j] = emb4[(size_t)word[j] * 32 + lane32];

        #pragma unroll
        for (int j = 0; j < 10; ++j) {
            float p = v[j].x * ws4.x + v[j].y * ws4.y + v[j].z * ws4.z + v[j].w * ws4.w;
            p += __shfl_xor(p, 16, 64);
            p += __shfl_xor(p, 8, 64);
            p += __shfl_xor(p, 4, 64);
            p += __shfl_xor(p, 2, 64);
            p += __shfl_xor(p, 1, 64);
            float e = fast_exp_tanh(p + bs);
            esum += e;
            acc.x += e * v[j].x;
            acc.y += e * v[j].y;
            acc.z += e * v[j].z;
            acc.w += e * v[j].w;
        }
    }

    float inv = 1.0f / esum;
    acc.x *= inv; acc.y *= inv; acc.z *= inv; acc.w *= inv;
    ((float4*)outp)[lane32] = acc;
}

// ---------------- Kernel B: pv[b,d] = sum_h tanh(q@Wq+bq)[b,d*64+h]*w_red[h] -
// Per-thread tile 8m x 4n; q rows direct from global (L2-resident, broadcast),
// double-buffered k4 prefetch; only Wq staged in LDS.
__global__ __launch_bounds__(256) void pv_kernel(
    const float* __restrict__ q_emb, const float* __restrict__ Wq,
    const float* __restrict__ bq, const float* __restrict__ w_red,
    float* __restrict__ pv)
{
    __shared__ __align__(16) float Wb[128 * 68];    // 34.8 KB

    int dd  = blockIdx.x;          // 0..127
    int m0g = blockIdx.y * 128;    // row offset (0 or 128)
    int tid = threadIdx.x;

    {
        int rrow = tid >> 4;
        int f4   = tid & 15;
        #pragma unroll
        for (int pass = 0; pass < 8; ++pass) {
            int k = pass * 16 + rrow;
            float4 vw = ((const float4*)Wq)[k * 2048 + dd * 16 + f4];
            *(float4*)&Wb[k * 68 + f4 * 4] = vw;
        }
    }
    __syncthreads();

    int nthr = tid & 15;
    int mthr = tid >> 4;
    int n0 = nthr * 4;
    const float4* q4 = (const float4*)q_emb;
    int mbase = (m0g + mthr * 8) * 32;

    float acc[8][4];
    #pragma unroll
    for (int i = 0; i < 8; ++i)
        #pragma unroll
        for (int j = 0; j < 4; ++j) acc[i][j] = 0.f;

    float4 qa[8], qb[8];
    #pragma unroll
    for (int i = 0; i < 8; ++i) qa[i] = q4[mbase + i * 32];

    for (int k4 = 0; k4 < 32; ++k4) {
        if (k4 < 31) {
            #pragma unroll
            for (int i = 0; i < 8; ++i) qb[i] = q4[mbase + i * 32 + k4 + 1];
        }
        #pragma unroll
        for (int kk = 0; kk < 4; ++kk) {
            float4 wv = *(const float4*)&Wb[(k4 * 4 + kk) * 68 + n0];
            #pragma unroll
            for (int i = 0; i < 8; ++i) {
                float a = (kk == 0) ? qa[i].x : (kk == 1) ? qa[i].y
                        : (kk == 2) ? qa[i].z : qa[i].w;
                acc[i][0] += a * wv.x;
                acc[i][1] += a * wv.y;
                acc[i][2] += a * wv.z;
                acc[i][3] += a * wv.w;
            }
        }
        #pragma unroll
        for (int i = 0; i < 8; ++i) qa[i] = qb[i];
    }

    float4 bqv = ((const float4*)bq)[dd * 16 + nthr];
    float4 wrv = ((const float4*)w_red)[nthr];

    #pragma unroll
    for (int i = 0; i < 8; ++i) {
        float s = fast_tanh(acc[i][0] + bqv.x) * wrv.x
                + fast_tanh(acc[i][1] + bqv.y) * wrv.y
                + fast_tanh(acc[i][2] + bqv.z) * wrv.z
                + fast_tanh(acc[i][3] + bqv.w) * wrv.w;
        s += __shfl_xor(s, 1, 64);
        s += __shfl_xor(s, 2, 64);
        s += __shfl_xor(s, 4, 64);
        s += __shfl_xor(s, 8, 64);
        if (nthr == 0) pv[(m0g + mthr * 8 + i) * 128 + dd] = s;
    }
}

// ---------------- Kernel C: review attention + output ------------------------
__global__ __launch_bounds__(256) void attn_kernel(
    const float* __restrict__ user_emb, const float* __restrict__ item_emb,
    const float* __restrict__ q_emb, const float* __restrict__ pv,
    const float* __restrict__ pf, float* __restrict__ out)
{
    __shared__ float rev[R * 129];
    __shared__ float pvl[D];
    __shared__ float sc[R];

    int b   = blockIdx.x;
    int set = blockIdx.y;
    const float* revg = (set == 0 ? user_emb : item_emb) + b * R * D;
    int tid = threadIdx.x;

    for (int idx = tid; idx < R * D; idx += 256)
        rev[(idx >> 7) * 129 + (idx & 127)] = revg[idx];
    if (tid < D) pvl[tid] = pv[b * D + tid];
    __syncthreads();

    if (tid < R) {
        float s = 0.f;
        const float* row = &rev[tid * 129];
        #pragma unroll 16
        for (int k = 0; k < D; ++k) s += row[k] * pvl[k];
        sc[tid] = s;
    }
    __syncthreads();

    float m = -1e30f;
    for (int r = 0; r < R; ++r) m = fmaxf(m, sc[r]);
    float sum = 0.f;
    for (int r = 0; r < R; ++r) sum += __expf(sc[r] - m);
    float inv = 1.f / sum;

    if (tid < D) {
        float acc = 0.f;
        for (int r = 0; r < R; ++r)
            acc += __expf(sc[r] - m) * inv * rev[r * 129 + tid];
        if (set == 0) {
            acc += pf[0] * q_emb[b * D + tid];
            out[b * D + tid] = acc;
        } else {
            out[NB * D + b * D + tid] = acc;
        }
    }
}

extern "C" void kernel_launch(void* const* d_in, const int* in_sizes, int n_in,
                              void* d_out, int out_size, void* d_ws, size_t ws_size,
                              hipStream_t stream) {
    const int*   user_w  = (const int*)d_in[0];
    const int*   item_w  = (const int*)d_in[1];
    const int*   query_w = (const int*)d_in[2];
    const float* emb     = (const float*)d_in[3];
    const float* w_self  = (const float*)d_in[4];
    const float* b_self  = (const float*)d_in[5];
    const float* Wq      = (const float*)d_in[6];
    const float* bq      = (const float*)d_in[7];
    const float* w_red   = (const float*)d_in[8];
    const float* pf      = (const float*)d_in[9];

    float* ws       = (float*)d_ws;
    float* user_emb = ws;                          // 5120*128
    float* item_emb = user_emb + NDOC_UI * D;      // 5120*128
    float* q_emb    = item_emb + NDOC_UI * D;      // 256*128
    float* pv       = q_emb    + NB * D;           // 256*128
    float* evocab   = pv       + NB * D;           // 50000
    ushort* emb_bf  = (ushort*)(evocab + VOCAB);   // 4 quarter-tables, 12.8 MB
    float* out      = (float*)d_out;

    // Fast path needs the bf16 vocab table in ws; guard against small ws.
    const size_t need_fast =
        (size_t)(2 * NDOC_UI * D + 2 * NB * D + VOCAB) * sizeof(float)
        + (size_t)VOCAB * D * sizeof(ushort);      // 18,505,024 B

    if (ws_size >= need_fast) {
        vocab_prep_kernel<<<VOCAB / 8, 256, 0, stream>>>(
            emb, w_self, b_self, emb_bf, evocab);
        doc_embed_bf16_kernel<<<NDOC, 128, 0, stream>>>(
            user_w, item_w, query_w, emb_bf, evocab, user_emb, item_emb, q_emb);
    } else {
        doc_embed_fp32_kernel<<<NDOC / 8, 256, 0, stream>>>(
            user_w, item_w, query_w, emb, w_self, b_self, user_emb, item_emb, q_emb);
    }
    pv_kernel<<<dim3(128, 2), 256, 0, stream>>>(q_emb, Wq, bq, w_red, pv);
    attn_kernel<<<dim3(NB, 2), 256, 0, stream>>>(user_emb, item_emb, q_emb, pv, pf, out);
}